// Round 2
// baseline (4900.150 us; speedup 1.0000x reference)
//
#include <hip/hip_runtime.h>
#include <math.h>

// -------------------------------------------------------------------------
// VQ-VAE forward, fp32 direct kernels (round 2: same logic as R1, workspace
// shrunk 176->134 MB via aliasing in case ws_size overflow killed the
// container). Layout NCHW everywhere, matching the JAX reference.
//
// Workspace plan (floats):
//   A = ws            : 16,777,216 (64 MB)  conv0 out -> (free) -> z/q -> up0 out
//   B = A + 16777216  :  8,388,608 (32 MB)  conv1 out -> enc-res temp -> dec h
//   C = B + 8388608   :  8,388,608 (32 MB)  enc h2 -> (free) -> dec-res temp
//   total 33,554,432 floats = 134.2 MB
// -------------------------------------------------------------------------

// ---------------- conv 4x4 stride2 pad1 ----------------
template<int CIN, int COT, bool RELU_OUT>
__global__ __launch_bounds__(256) void conv4s2_kernel(
    const float* __restrict__ x, const float* __restrict__ w,
    const float* __restrict__ b, float* __restrict__ y,
    int Hin, int Win, int Cout) {
  const int Hout = Hin >> 1, Wout = Win >> 1;
  int t = blockIdx.x * 256 + threadIdx.x;
  if (t >= Hout * Wout) return;
  const int wo = t % Wout, ho = t / Wout;
  const int cog = blockIdx.y, n = blockIdx.z;
  const int co0 = cog * COT;

  float acc[COT];
#pragma unroll
  for (int u = 0; u < COT; u++) acc[u] = b[co0 + u];

  const int ih0 = 2 * ho - 1, iw0 = 2 * wo - 1;
  for (int ci = 0; ci < CIN; ci++) {
    const float* xp = x + ((size_t)(n * CIN + ci)) * Hin * Win;
    const float* wp = w + ((size_t)(co0 * CIN + ci)) * 16;
#pragma unroll
    for (int kh = 0; kh < 4; kh++) {
      int ih = ih0 + kh;
      if ((unsigned)ih < (unsigned)Hin) {
        const float* xr = xp + ih * Win;
#pragma unroll
        for (int kw = 0; kw < 4; kw++) {
          int iw = iw0 + kw;
          if ((unsigned)iw < (unsigned)Win) {
            float xv = xr[iw];
#pragma unroll
            for (int u = 0; u < COT; u++)
              acc[u] = fmaf(xv, wp[u * CIN * 16 + kh * 4 + kw], acc[u]);
          }
        }
      }
    }
  }
#pragma unroll
  for (int u = 0; u < COT; u++) {
    float v = acc[u];
    if (RELU_OUT) v = fmaxf(v, 0.f);
    y[(((size_t)(n * Cout + co0 + u)) * Hout + ho) * Wout + wo] = v;
  }
}

// ---------------- conv 3x3 stride1 pad1 ----------------
template<int CIN, int COT, bool RELU_IN, bool RELU_OUT>
__global__ __launch_bounds__(256) void conv3s1_kernel(
    const float* __restrict__ x, const float* __restrict__ w,
    const float* __restrict__ b, float* __restrict__ y,
    int H, int W, int Cout) {
  int t = blockIdx.x * 256 + threadIdx.x;
  if (t >= H * W) return;
  const int wo = t % W, ho = t / W;
  const int cog = blockIdx.y, n = blockIdx.z;
  const int co0 = cog * COT;

  float acc[COT];
#pragma unroll
  for (int u = 0; u < COT; u++) acc[u] = b[co0 + u];

  for (int ci = 0; ci < CIN; ci++) {
    const float* xp = x + ((size_t)(n * CIN + ci)) * H * W;
    const float* wp = w + ((size_t)(co0 * CIN + ci)) * 9;
#pragma unroll
    for (int kh = 0; kh < 3; kh++) {
      int ih = ho - 1 + kh;
      if ((unsigned)ih < (unsigned)H) {
        const float* xr = xp + ih * W;
#pragma unroll
        for (int kw = 0; kw < 3; kw++) {
          int iw = wo - 1 + kw;
          if ((unsigned)iw < (unsigned)W) {
            float xv = xr[iw];
            if (RELU_IN) xv = fmaxf(xv, 0.f);
#pragma unroll
            for (int u = 0; u < COT; u++)
              acc[u] = fmaf(xv, wp[u * CIN * 9 + kh * 3 + kw], acc[u]);
          }
        }
      }
    }
  }
#pragma unroll
  for (int u = 0; u < COT; u++) {
    float v = acc[u];
    if (RELU_OUT) v = fmaxf(v, 0.f);
    y[(((size_t)(n * Cout + co0 + u)) * H + ho) * W + wo] = v;
  }
}

// ---------------- conv 1x1 ----------------
template<int CIN, int COT, bool RELU_IN, bool ACCUM>
__global__ __launch_bounds__(256) void conv1x1_kernel(
    const float* __restrict__ x, const float* __restrict__ w,
    const float* __restrict__ b, float* __restrict__ y,
    int HW, int Cout) {
  int t = blockIdx.x * 256 + threadIdx.x;
  if (t >= HW) return;
  const int cog = blockIdx.y, n = blockIdx.z;
  const int co0 = cog * COT;

  float acc[COT];
#pragma unroll
  for (int u = 0; u < COT; u++) acc[u] = b[co0 + u];

  for (int ci = 0; ci < CIN; ci++) {
    float xv = x[((size_t)(n * CIN + ci)) * HW + t];
    if (RELU_IN) xv = fmaxf(xv, 0.f);
#pragma unroll
    for (int u = 0; u < COT; u++)
      acc[u] = fmaf(xv, w[(co0 + u) * CIN + ci], acc[u]);
  }
#pragma unroll
  for (int u = 0; u < COT; u++) {
    size_t idx = ((size_t)(n * Cout + co0 + u)) * HW + t;
    if (ACCUM) y[idx] = y[idx] + acc[u];
    else       y[idx] = acc[u];
  }
}

// ---------------- ConvTranspose 4x4 stride2 pad1 ----------------
// torch semantics, weight (CIN, Cout, 4, 4). Each thread computes an
// (even,odd) ow pair so kw is loop-uniform; x rows shared.
template<int CIN, int COT, bool RELU_IN, bool RELU_OUT>
__global__ __launch_bounds__(256) void convt4s2_kernel(
    const float* __restrict__ x, const float* __restrict__ w,
    const float* __restrict__ b, float* __restrict__ y,
    int Hin, int Win, int Cout) {
  const int Hout = Hin * 2;
  const int Wh = Win;  // output width / 2
  int t = blockIdx.x * 256 + threadIdx.x;
  if (t >= Hout * Wh) return;
  const int a = t % Wh, oh = t / Wh;
  const int cog = blockIdx.y, n = blockIdx.z;
  const int co0 = cog * COT;

  float acc0[COT], acc1[COT];  // ow=2a (even), ow=2a+1 (odd)
#pragma unroll
  for (int u = 0; u < COT; u++) { acc0[u] = b[co0 + u]; acc1[u] = b[co0 + u]; }

  const int kh0 = (oh + 1) & 1;
#pragma unroll
  for (int dh = 0; dh < 2; dh++) {
    int kh = kh0 + 2 * dh;
    int ih = (oh + 1 - kh) >> 1;
    if (ih >= 0 && ih < Hin) {
      for (int ci = 0; ci < CIN; ci++) {
        const float* xr = x + (((size_t)(n * CIN + ci)) * Hin + ih) * Win;
        float x0  = xr[a];
        float xm1 = (a > 0)        ? xr[a - 1] : 0.f;
        float xp1 = (a + 1 < Win)  ? xr[a + 1] : 0.f;
        if (RELU_IN) {
          x0 = fmaxf(x0, 0.f); xm1 = fmaxf(xm1, 0.f); xp1 = fmaxf(xp1, 0.f);
        }
        const float* wp = w + ((size_t)(ci * Cout + co0)) * 16 + kh * 4;
#pragma unroll
        for (int u = 0; u < COT; u++) {
          float w0 = wp[u * 16 + 0], w1 = wp[u * 16 + 1];
          float w2 = wp[u * 16 + 2], w3 = wp[u * 16 + 3];
          acc0[u] = fmaf(x0,  w1, acc0[u]);   // even: kw=1 -> iw=a
          acc0[u] = fmaf(xm1, w3, acc0[u]);   // even: kw=3 -> iw=a-1
          acc1[u] = fmaf(xp1, w0, acc1[u]);   // odd:  kw=0 -> iw=a+1
          acc1[u] = fmaf(x0,  w2, acc1[u]);   // odd:  kw=2 -> iw=a
        }
      }
    }
  }
#pragma unroll
  for (int u = 0; u < COT; u++) {
    float v0 = acc0[u], v1 = acc1[u];
    if (RELU_OUT) { v0 = fmaxf(v0, 0.f); v1 = fmaxf(v1, 0.f); }
    float* row = y + (((size_t)(n * Cout + co0 + u)) * Hout + oh) * (2 * Win);
    ((float2*)row)[a] = make_float2(v0, v1);
  }
}

// ---------------- Vector quantizer (IN-PLACE: q aliases z) ----------------
// z: (16,64,64,64) NCHW; cb: (64,512). Each thread owns one spatial position's
// whole channel column: reads it fully into registers, then overwrites it with
// the selected code vector -> in-place is race-free. fp64 distance accum with
// strict-< (first-min) to match numpy argmin.
__global__ __launch_bounds__(256) void vq_kernel(
    const float* __restrict__ cb, float* __restrict__ zq) {
  __shared__ float cbs[64 * 64];   // one 64-code tile, [d][kk]
  __shared__ double cbn[64];
  const int tid = threadIdx.x;
  const int p = blockIdx.x * 256 + tid;       // 65536 positions exactly
  const int n = p >> 12, hw = p & 4095;
  float* zp = zq + ((size_t)n) * 64 * 4096 + hw;
  float zr[64];
#pragma unroll
  for (int d = 0; d < 64; d++) zr[d] = zp[d * 4096];

  int best = 0;
  double bestd = 1e300;
  for (int kt = 0; kt < 8; kt++) {
    __syncthreads();
    for (int i = tid; i < 4096; i += 256) {
      int d = i >> 6, kk = i & 63;
      cbs[i] = cb[d * 512 + kt * 64 + kk];
    }
    __syncthreads();
    if (tid < 64) {
      double s = 0.0;
      for (int d = 0; d < 64; d++) {
        double c = (double)cbs[d * 64 + tid];
        s = fma(c, c, s);
      }
      cbn[tid] = s;
    }
    __syncthreads();
    for (int kk = 0; kk < 64; kk++) {
      double dot = 0.0;
#pragma unroll
      for (int d = 0; d < 64; d++)
        dot = fma((double)zr[d], (double)cbs[d * 64 + kk], dot);
      double dist = cbn[kk] - 2.0 * dot;
      int k = kt * 64 + kk;
      if (dist < bestd) { bestd = dist; best = k; }
    }
  }
#pragma unroll
  for (int d = 0; d < 64; d++) zp[d * 4096] = cb[d * 512 + best];
}

// -------------------------------------------------------------------------
extern "C" void kernel_launch(void* const* d_in, const int* in_sizes, int n_in,
                              void* d_out, int out_size, void* d_ws, size_t ws_size,
                              hipStream_t stream) {
  const float* x          = (const float*)d_in[0];
  const float* enc_w0     = (const float*)d_in[1];
  const float* enc_b0     = (const float*)d_in[2];
  const float* enc_w1     = (const float*)d_in[3];
  const float* enc_b1     = (const float*)d_in[4];
  const float* enc_wf     = (const float*)d_in[5];
  const float* enc_bf     = (const float*)d_in[6];
  const float* enc_res_w1 = (const float*)d_in[7];
  const float* enc_res_b1 = (const float*)d_in[8];
  const float* enc_res_w2 = (const float*)d_in[9];
  const float* enc_res_b2 = (const float*)d_in[10];
  const float* pre_w      = (const float*)d_in[11];
  const float* pre_b      = (const float*)d_in[12];
  const float* codebook   = (const float*)d_in[13];
  const float* dec_w      = (const float*)d_in[14];
  const float* dec_b      = (const float*)d_in[15];
  const float* dec_res_w1 = (const float*)d_in[16];
  const float* dec_res_b1 = (const float*)d_in[17];
  const float* dec_res_w2 = (const float*)d_in[18];
  const float* dec_res_b2 = (const float*)d_in[19];
  const float* up_w0      = (const float*)d_in[20];
  const float* up_b0      = (const float*)d_in[21];
  const float* up_w1      = (const float*)d_in[22];
  const float* up_b1      = (const float*)d_in[23];
  float* out = (float*)d_out;

  float* A = (float*)d_ws;         // 16,777,216 floats (64 MB)
  float* B = A + 16777216;         //  8,388,608 floats (32 MB)
  float* C = B + 8388608;          //  8,388,608 floats (32 MB)
  // total: 134.2 MB

  const dim3 blk(256);
  const int N = 16;

  // --- Encoder ---
  // conv0: x(16,3,256,256) -> A(16,64,128,128), ReLU
  conv4s2_kernel<3, 4, true><<<dim3(64, 16, N), blk, 0, stream>>>(
      x, enc_w0, enc_b0, A, 256, 256, 64);
  // conv1: A -> B(16,128,64,64), ReLU
  conv4s2_kernel<64, 8, true><<<dim3(16, 16, N), blk, 0, stream>>>(
      A, enc_w1, enc_b1, B, 128, 128, 128);
  // convf: B -> C(16,128,64,64)
  conv3s1_kernel<128, 8, false, false><<<dim3(16, 16, N), blk, 0, stream>>>(
      B, enc_wf, enc_bf, C, 64, 64, 128);
  // enc residual stack: h=C, temp=B (free)
  for (int i = 0; i < 2; i++) {
    conv3s1_kernel<128, 8, true, false><<<dim3(16, 4, N), blk, 0, stream>>>(
        C, enc_res_w1 + (size_t)i * 32 * 128 * 9, enc_res_b1 + i * 32,
        B, 64, 64, 32);
    conv1x1_kernel<32, 8, true, true><<<dim3(16, 16, N), blk, 0, stream>>>(
        B, enc_res_w2 + (size_t)i * 128 * 32, enc_res_b2 + i * 128,
        C, 4096, 128);
  }
  // pre: relu(C) -> z in A (A free after conv1), (16,64,64,64)
  conv1x1_kernel<128, 8, true, false><<<dim3(16, 8, N), blk, 0, stream>>>(
      C, pre_w, pre_b, A, 4096, 64);

  // --- VQ (in-place on A) ---
  vq_kernel<<<dim3(256), blk, 0, stream>>>(codebook, A);

  // --- Decoder ---
  // dec: q(A) -> B(16,128,64,64)
  conv3s1_kernel<64, 8, false, false><<<dim3(16, 16, N), blk, 0, stream>>>(
      A, dec_w, dec_b, B, 64, 64, 128);
  // dec residual stack: h=B, temp=C (free)
  for (int i = 0; i < 2; i++) {
    conv3s1_kernel<128, 8, true, false><<<dim3(16, 4, N), blk, 0, stream>>>(
        B, dec_res_w1 + (size_t)i * 32 * 128 * 9, dec_res_b1 + i * 32,
        C, 64, 64, 32);
    conv1x1_kernel<32, 8, true, true><<<dim3(16, 16, N), blk, 0, stream>>>(
        C, dec_res_w2 + (size_t)i * 128 * 32, dec_res_b2 + i * 128,
        B, 4096, 128);
  }
  // up0: relu(B) -> A(16,64,128,128), ReLU  (A free after dec conv consumed q)
  convt4s2_kernel<128, 8, true, true><<<dim3(32, 8, N), blk, 0, stream>>>(
      B, up_w0, up_b0, A, 64, 64, 64);
  // up1: A -> out(16,3,256,256)
  convt4s2_kernel<64, 3, false, false><<<dim3(128, 1, N), blk, 0, stream>>>(
      A, up_w1, up_b1, out, 128, 128, 3);
}

// Round 3
// 3105.018 us; speedup vs baseline: 1.5781x; 1.5781x over previous
//
#include <hip/hip_runtime.h>
#include <math.h>

// -------------------------------------------------------------------------
// VQ-VAE forward, fp32 direct kernels, round 3: wave-uniform row indices
// (readfirstlane) so weight loads scalarize to s_load; x boundary via
// clamp+select instead of divergent guards. Same math/accumulation order.
// Workspace: A(64MB) B(32MB) C(32MB) = 134.2 MB, aliased as in R2.
// -------------------------------------------------------------------------

#define DEV __device__ __forceinline__

DEV int rfl(int v) { return __builtin_amdgcn_readfirstlane(v); }

// ---------------- conv 4x4 stride2 pad1, one output row per wave ----------
// OW = output width (64 or 128, multiple of 64 so t/OW is wave-uniform).
template<int CIN, int COT, bool RELU_OUT, int OW>
__global__ __launch_bounds__(256) void conv4s2_row(
    const float* __restrict__ x, const float* __restrict__ w,
    const float* __restrict__ bias, float* __restrict__ y,
    int Hout, int Cout) {
  const int Win = OW * 2, Hin = Hout * 2;
  const int t = blockIdx.x * 256 + threadIdx.x;
  const int wo = t & (OW - 1);
  const int ho = rfl(t / OW);                 // wave-uniform
  const int co0 = blockIdx.y * COT, n = blockIdx.z;

  float acc[COT];
#pragma unroll
  for (int u = 0; u < COT; u++) acc[u] = bias[co0 + u];

  const int iw0 = 2 * wo - 1;                 // taps at iw0 .. iw0+3
  const int cA = iw0 < 0 ? 0 : iw0;           // clamped col for kw=0
  const bool mA = iw0 >= 0;
  const int cD = (iw0 + 3 < Win) ? iw0 + 3 : Win - 1;  // kw=3
  const bool mD = iw0 + 3 < Win;

  for (int ci = 0; ci < CIN; ci++) {
    const float* xp = x + ((size_t)(n * CIN + ci)) * Hin * Win;
    const float* wp = w + ((size_t)(co0 * CIN + ci)) * 16;
#pragma unroll
    for (int kh = 0; kh < 4; kh++) {
      const int ih = 2 * ho - 1 + kh;         // scalar
      if (ih >= 0 && ih < Hin) {              // uniform branch
        const float* row = xp + (size_t)ih * Win;
        float x0 = row[cA];      x0 = mA ? x0 : 0.f;
        float x1 = row[iw0 + 1];               // 2wo   : always in range
        float x2 = row[iw0 + 2];               // 2wo+1 : always in range
        float x3 = row[cD];      x3 = mD ? x3 : 0.f;
#pragma unroll
        for (int u = 0; u < COT; u++) {
          const float* wr = wp + u * CIN * 16 + kh * 4;  // uniform -> s_load
          acc[u] = fmaf(x0, wr[0], acc[u]);
          acc[u] = fmaf(x1, wr[1], acc[u]);
          acc[u] = fmaf(x2, wr[2], acc[u]);
          acc[u] = fmaf(x3, wr[3], acc[u]);
        }
      }
    }
  }
#pragma unroll
  for (int u = 0; u < COT; u++) {
    float v = acc[u];
    if (RELU_OUT) v = fmaxf(v, 0.f);
    y[(((size_t)(n * Cout + co0 + u)) * Hout + ho) * OW + wo] = v;
  }
}

// ---------------- conv 3x3 stride1 pad1 on 64x64, one row per wave --------
template<int CIN, int COT, bool RELU_IN, bool RELU_OUT>
__global__ __launch_bounds__(256) void conv3_64(
    const float* __restrict__ x, const float* __restrict__ w,
    const float* __restrict__ bias, float* __restrict__ y, int Cout) {
  const int lane = threadIdx.x & 63;
  const int ho = rfl(blockIdx.x * 4 + (threadIdx.x >> 6));   // wave-uniform
  const int co0 = blockIdx.y * COT, n = blockIdx.z;

  float acc[COT];
#pragma unroll
  for (int u = 0; u < COT; u++) acc[u] = bias[co0 + u];

  const int cm = lane > 0 ? lane - 1 : 0;     // clamped col, kw=0
  const bool mm = lane > 0;
  const int cp = lane < 63 ? lane + 1 : 63;   // kw=2
  const bool mp = lane < 63;

  for (int ci = 0; ci < CIN; ci++) {
    const float* xp = x + ((size_t)(n * CIN + ci)) * 4096;
    const float* wp = w + ((size_t)(co0 * CIN + ci)) * 9;
#pragma unroll
    for (int kh = 0; kh < 3; kh++) {
      const int ih = ho - 1 + kh;             // scalar
      if (ih >= 0 && ih < 64) {               // uniform branch
        const float* row = xp + (ih << 6);
        float xa = row[cm];   xa = mm ? xa : 0.f;
        float x0 = row[lane];
        float xb = row[cp];   xb = mp ? xb : 0.f;
        if (RELU_IN) {
          xa = fmaxf(xa, 0.f); x0 = fmaxf(x0, 0.f); xb = fmaxf(xb, 0.f);
        }
#pragma unroll
        for (int u = 0; u < COT; u++) {
          const float* wr = wp + u * CIN * 9 + kh * 3;     // uniform -> s_load
          acc[u] = fmaf(xa, wr[0], acc[u]);
          acc[u] = fmaf(x0, wr[1], acc[u]);
          acc[u] = fmaf(xb, wr[2], acc[u]);
        }
      }
    }
  }
#pragma unroll
  for (int u = 0; u < COT; u++) {
    float v = acc[u];
    if (RELU_OUT) v = fmaxf(v, 0.f);
    y[(((size_t)(n * Cout + co0 + u)) * 64 + ho) * 64 + lane] = v;
  }
}

// ---------------- conv 1x1 (weights already uniform/unconditional) --------
template<int CIN, int COT, bool RELU_IN, bool ACCUM>
__global__ __launch_bounds__(256) void conv1x1_kernel(
    const float* __restrict__ x, const float* __restrict__ w,
    const float* __restrict__ bias, float* __restrict__ y,
    int HW, int Cout) {
  const int t = blockIdx.x * 256 + threadIdx.x;
  const int cog = blockIdx.y, n = blockIdx.z;
  const int co0 = cog * COT;

  float acc[COT];
#pragma unroll
  for (int u = 0; u < COT; u++) acc[u] = bias[co0 + u];

  for (int ci = 0; ci < CIN; ci++) {
    float xv = x[((size_t)(n * CIN + ci)) * HW + t];
    if (RELU_IN) xv = fmaxf(xv, 0.f);
#pragma unroll
    for (int u = 0; u < COT; u++)
      acc[u] = fmaf(xv, w[(co0 + u) * CIN + ci], acc[u]);
  }
#pragma unroll
  for (int u = 0; u < COT; u++) {
    size_t idx = ((size_t)(n * Cout + co0 + u)) * HW + t;
    if (ACCUM) y[idx] = y[idx] + acc[u];
    else       y[idx] = acc[u];
  }
}

// ---------------- ConvTranspose 4x4 stride2 pad1, one out-row per wave ----
// WH = Win = half output width (64 or 128). Thread owns (even,odd) ow pair.
template<int CIN, int COT, bool RELU_IN, bool RELU_OUT, int WH>
__global__ __launch_bounds__(256) void convt_row(
    const float* __restrict__ x, const float* __restrict__ w,
    const float* __restrict__ bias, float* __restrict__ y,
    int Hin, int Cout) {
  const int Hout = Hin * 2;
  const int t = blockIdx.x * 256 + threadIdx.x;
  const int a = t & (WH - 1);
  const int oh = rfl(t / WH);                 // wave-uniform
  const int co0 = blockIdx.y * COT, n = blockIdx.z;

  float acc0[COT], acc1[COT];
#pragma unroll
  for (int u = 0; u < COT; u++) { acc0[u] = bias[co0 + u]; acc1[u] = bias[co0 + u]; }

  const int cm = a > 0 ? a - 1 : 0;
  const bool mm = a > 0;
  const int cp = a < WH - 1 ? a + 1 : WH - 1;
  const bool mp = a < WH - 1;

  const int kh0 = (oh + 1) & 1;               // scalar
#pragma unroll
  for (int dh = 0; dh < 2; dh++) {
    const int kh = kh0 + 2 * dh;
    const int ih = (oh + 1 - kh) >> 1;        // scalar
    if (ih >= 0 && ih < Hin) {                // uniform branch
      for (int ci = 0; ci < CIN; ci++) {
        const float* row = x + (((size_t)(n * CIN + ci)) * Hin + ih) * WH;
        float x0  = row[a];
        float xm1 = row[cm];  xm1 = mm ? xm1 : 0.f;
        float xp1 = row[cp];  xp1 = mp ? xp1 : 0.f;
        if (RELU_IN) {
          x0 = fmaxf(x0, 0.f); xm1 = fmaxf(xm1, 0.f); xp1 = fmaxf(xp1, 0.f);
        }
        const float* wp = w + ((size_t)(ci * Cout + co0)) * 16 + kh * 4;
#pragma unroll
        for (int u = 0; u < COT; u++) {
          const float* wr = wp + u * 16;      // uniform -> s_load
          acc0[u] = fmaf(x0,  wr[1], acc0[u]);   // even ow=2a : kw=1 -> iw=a
          acc0[u] = fmaf(xm1, wr[3], acc0[u]);   //             kw=3 -> iw=a-1
          acc1[u] = fmaf(xp1, wr[0], acc1[u]);   // odd ow=2a+1: kw=0 -> iw=a+1
          acc1[u] = fmaf(x0,  wr[2], acc1[u]);   //             kw=2 -> iw=a
        }
      }
    }
  }
#pragma unroll
  for (int u = 0; u < COT; u++) {
    float v0 = acc0[u], v1 = acc1[u];
    if (RELU_OUT) { v0 = fmaxf(v0, 0.f); v1 = fmaxf(v1, 0.f); }
    float* row = y + (((size_t)(n * Cout + co0 + u)) * Hout + oh) * (2 * WH);
    ((float2*)row)[a] = make_float2(v0, v1);
  }
}

// ---------------- Vector quantizer (in-place, fp64 exact argmin) ----------
__global__ __launch_bounds__(256) void vq_kernel(
    const float* __restrict__ cb, float* __restrict__ zq) {
  __shared__ float cbs[64 * 64];
  __shared__ double cbn[64];
  const int tid = threadIdx.x;
  const int p = blockIdx.x * 256 + tid;
  const int n = p >> 12, hw = p & 4095;
  float* zp = zq + ((size_t)n) * 64 * 4096 + hw;
  float zr[64];
#pragma unroll
  for (int d = 0; d < 64; d++) zr[d] = zp[d * 4096];

  int best = 0;
  double bestd = 1e300;
  for (int kt = 0; kt < 8; kt++) {
    __syncthreads();
    for (int i = tid; i < 4096; i += 256) {
      int d = i >> 6, kk = i & 63;
      cbs[i] = cb[d * 512 + kt * 64 + kk];
    }
    __syncthreads();
    if (tid < 64) {
      double s = 0.0;
      for (int d = 0; d < 64; d++) {
        double c = (double)cbs[d * 64 + tid];
        s = fma(c, c, s);
      }
      cbn[tid] = s;
    }
    __syncthreads();
    for (int kk = 0; kk < 64; kk++) {
      double dot = 0.0;
#pragma unroll
      for (int d = 0; d < 64; d++)
        dot = fma((double)zr[d], (double)cbs[d * 64 + kk], dot);
      double dist = cbn[kk] - 2.0 * dot;
      int k = kt * 64 + kk;
      if (dist < bestd) { bestd = dist; best = k; }
    }
  }
#pragma unroll
  for (int d = 0; d < 64; d++) zp[d * 4096] = cb[d * 512 + best];
}

// -------------------------------------------------------------------------
extern "C" void kernel_launch(void* const* d_in, const int* in_sizes, int n_in,
                              void* d_out, int out_size, void* d_ws, size_t ws_size,
                              hipStream_t stream) {
  const float* x          = (const float*)d_in[0];
  const float* enc_w0     = (const float*)d_in[1];
  const float* enc_b0     = (const float*)d_in[2];
  const float* enc_w1     = (const float*)d_in[3];
  const float* enc_b1     = (const float*)d_in[4];
  const float* enc_wf     = (const float*)d_in[5];
  const float* enc_bf     = (const float*)d_in[6];
  const float* enc_res_w1 = (const float*)d_in[7];
  const float* enc_res_b1 = (const float*)d_in[8];
  const float* enc_res_w2 = (const float*)d_in[9];
  const float* enc_res_b2 = (const float*)d_in[10];
  const float* pre_w      = (const float*)d_in[11];
  const float* pre_b      = (const float*)d_in[12];
  const float* codebook   = (const float*)d_in[13];
  const float* dec_w      = (const float*)d_in[14];
  const float* dec_b      = (const float*)d_in[15];
  const float* dec_res_w1 = (const float*)d_in[16];
  const float* dec_res_b1 = (const float*)d_in[17];
  const float* dec_res_w2 = (const float*)d_in[18];
  const float* dec_res_b2 = (const float*)d_in[19];
  const float* up_w0      = (const float*)d_in[20];
  const float* up_b0      = (const float*)d_in[21];
  const float* up_w1      = (const float*)d_in[22];
  const float* up_b1      = (const float*)d_in[23];
  float* out = (float*)d_out;

  float* A = (float*)d_ws;         // 16,777,216 floats (64 MB)
  float* B = A + 16777216;         //  8,388,608 floats (32 MB)
  float* C = B + 8388608;          //  8,388,608 floats (32 MB)

  const dim3 blk(256);
  const int N = 16;

  // --- Encoder ---
  // conv0: x(16,3,256,256) -> A(16,64,128,128), ReLU
  conv4s2_row<3, 8, true, 128><<<dim3(64, 8, N), blk, 0, stream>>>(
      x, enc_w0, enc_b0, A, 128, 64);
  // conv1: A -> B(16,128,64,64), ReLU
  conv4s2_row<64, 16, true, 64><<<dim3(16, 8, N), blk, 0, stream>>>(
      A, enc_w1, enc_b1, B, 64, 128);
  // convf: B -> C(16,128,64,64)
  conv3_64<128, 16, false, false><<<dim3(16, 8, N), blk, 0, stream>>>(
      B, enc_wf, enc_bf, C, 128);
  // enc residual stack: h=C, temp=B
  for (int i = 0; i < 2; i++) {
    conv3_64<128, 8, true, false><<<dim3(16, 4, N), blk, 0, stream>>>(
        C, enc_res_w1 + (size_t)i * 32 * 128 * 9, enc_res_b1 + i * 32, B, 32);
    conv1x1_kernel<32, 8, true, true><<<dim3(16, 16, N), blk, 0, stream>>>(
        B, enc_res_w2 + (size_t)i * 128 * 32, enc_res_b2 + i * 128, C, 4096, 128);
  }
  // pre: relu(C) -> z in A
  conv1x1_kernel<128, 16, true, false><<<dim3(16, 4, N), blk, 0, stream>>>(
      C, pre_w, pre_b, A, 4096, 64);

  // --- VQ (in-place on A) ---
  vq_kernel<<<dim3(256), blk, 0, stream>>>(codebook, A);

  // --- Decoder ---
  // dec: q(A) -> B(16,128,64,64)
  conv3_64<64, 16, false, false><<<dim3(16, 8, N), blk, 0, stream>>>(
      A, dec_w, dec_b, B, 128);
  // dec residual stack: h=B, temp=C
  for (int i = 0; i < 2; i++) {
    conv3_64<128, 8, true, false><<<dim3(16, 4, N), blk, 0, stream>>>(
        B, dec_res_w1 + (size_t)i * 32 * 128 * 9, dec_res_b1 + i * 32, C, 32);
    conv1x1_kernel<32, 8, true, true><<<dim3(16, 16, N), blk, 0, stream>>>(
        C, dec_res_w2 + (size_t)i * 128 * 32, dec_res_b2 + i * 128, B, 4096, 128);
  }
  // up0: relu(B) -> A(16,64,128,128), ReLU
  convt_row<128, 8, true, true, 64><<<dim3(32, 8, N), blk, 0, stream>>>(
      B, up_w0, up_b0, A, 64, 64);
  // up1: A -> out(16,3,256,256)
  convt_row<64, 3, false, false, 128><<<dim3(128, 1, N), blk, 0, stream>>>(
      A, up_w1, up_b1, out, 128, 3);
}